// Round 1
// baseline (225.664 us; speedup 1.0000x reference)
//
#include <hip/hip_runtime.h>

#define B_ 2
#define T_ 4096
#define E_ 768
#define H_ 12
#define S_ 64
#define WIN_ 256

typedef unsigned short u16;
typedef unsigned int u32;
typedef __attribute__((ext_vector_type(8))) short bf16x8;
typedef __attribute__((ext_vector_type(4))) short bf16x4;
typedef __attribute__((ext_vector_type(4))) float f32x4;

__device__ __forceinline__ u16 f2bf(float f) {
  u32 u = __float_as_uint(f);
  u += ((u >> 16) & 1u) + 0x7fffu;   // RNE
  return (u16)(u >> 16);
}

__device__ __forceinline__ void async_copy16(const u16* g, u16* l) {
  __builtin_amdgcn_global_load_lds(
      (const __attribute__((address_space(1))) void*)g,
      (__attribute__((address_space(3))) void*)l, 16, 0, 0);
}

// ---------------- fp32 -> bf16, all 4 tensors in one dispatch ----------------
__global__ void cvt_all(const float* __restrict__ x, const float* __restrict__ wq,
                        const float* __restrict__ wk, const float* __restrict__ wv,
                        u16* __restrict__ xb, u16* __restrict__ wb) {
  const int n4x = B_ * T_ * E_ / 4;
  const int n4w = E_ * E_ / 4;
  int i = blockIdx.x * 256 + threadIdx.x;
  const float* src;
  u16* dst;
  int j;
  if (i < n4x) {
    src = x; dst = xb; j = i;
  } else {
    int t = i - n4x;
    int z = t / n4w;
    if (z >= 3) return;
    j = t - z * n4w;
    src = (z == 0) ? wq : ((z == 1) ? wk : wv);
    dst = wb + (size_t)z * E_ * E_;
  }
  float4 v = ((const float4*)src)[j];
  ushort4 o;
  o.x = f2bf(v.x); o.y = f2bf(v.y); o.z = f2bf(v.z); o.w = f2bf(v.w);
  ((ushort4*)dst)[j] = o;
}

// ---------------- QKV projection GEMM: 4-deep ring buffer, counted vmcnt ----------------
// K=768 -> 24 BK=32 steps. Old version drained vmcnt(0) at a __syncthreads every
// step (latency-bound: MfmaUtil 14%). New: prefetch 3 tiles ahead into a 4-slot
// LDS ring; per step wait only vmcnt(8) (tiles ki+1,ki+2 stay in flight) + one
// s_barrier. Prefetch index clamped so issue count is always 4/iter and the
// positional vmcnt arithmetic is exact.
__global__ __launch_bounds__(256)
void gemm_qkv(const u16* __restrict__ xb, const u16* __restrict__ wb,
              u16* __restrict__ qkv) {
  const int M = B_ * T_;
  __shared__ u16 As[4][4][128][8];   // [buf][kchunk][row][8]  32KB
  __shared__ u16 Bs[4][4][128][8];   // 32KB
  int tid = threadIdx.x;
  int lane = tid & 63, wave = tid >> 6;
  int wr = wave >> 1, wc = wave & 1;
  int q8 = lane >> 4, nl = lane & 15;
  int bm = blockIdx.x * 128, bn = blockIdx.y * 128;
  int z = blockIdx.z;
  const u16* A = xb;
  const u16* Bmat = wb + (size_t)z * E_ * E_;
  u16* C = qkv + (size_t)z * M * E_;
  float scale = (z == 0) ? (0.125f * 1.44269504088896f) : 1.0f;

  // staging addresses for this thread (2 A slots + 2 B slots)
  int ch0 = tid >> 7, row0 = tid & 127;
  int u1 = tid + 256;
  int ch1 = u1 >> 7, row1 = u1 & 127;
  const u16* ga0 = A + (size_t)(bm + row0) * E_ + ch0 * 8;
  const u16* ga1 = A + (size_t)(bm + row1) * E_ + ch1 * 8;
  const u16* gb0 = Bmat + (size_t)(bn + row0) * E_ + ch0 * 8;
  const u16* gb1 = Bmat + (size_t)(bn + row1) * E_ + ch1 * 8;

  const int NK = E_ / 32;   // 24
  // prologue: stage tiles 0..2 into bufs 0..2 (12 loads in flight per wave)
#pragma unroll
  for (int p = 0; p < 3; ++p) {
    int koff = p * 32;
    async_copy16(ga0 + koff, &As[p][ch0][row0][0]);
    async_copy16(ga1 + koff, &As[p][ch1][row1][0]);
    async_copy16(gb0 + koff, &Bs[p][ch0][row0][0]);
    async_copy16(gb1 + koff, &Bs[p][ch1][row1][0]);
  }

  f32x4 acc[4][4] = {};
  for (int ki = 0; ki < NK; ++ki) {
    // my tile-ki loads landed (8 newer stay in flight); all my prior ds_reads done
    asm volatile("s_waitcnt vmcnt(8) lgkmcnt(0)" ::: "memory");
    // after this barrier: ALL waves' tile-ki loads landed, and all waves are
    // done reading buf[(ki-1)&3] (so it is safe to overwrite it below)
    __builtin_amdgcn_s_barrier();
    __builtin_amdgcn_sched_barrier(0);

    // prefetch tile ki+3 (clamped) into buf (ki+3)&3 == buf (ki-1)&3
    {
      int kp = (ki + 3 < NK) ? ki + 3 : NK - 1;
      int nb = (ki + 3) & 3;
      int koff = kp * 32;
      async_copy16(ga0 + koff, &As[nb][ch0][row0][0]);
      async_copy16(ga1 + koff, &As[nb][ch1][row1][0]);
      async_copy16(gb0 + koff, &Bs[nb][ch0][row0][0]);
      async_copy16(gb1 + koff, &Bs[nb][ch1][row1][0]);
    }

    int buf = ki & 3;
    bf16x8 af[4], bfr[4];
#pragma unroll
    for (int i = 0; i < 4; ++i)
      af[i] = *(const bf16x8*)&As[buf][q8][wr * 64 + i * 16 + nl][0];
#pragma unroll
    for (int i = 0; i < 4; ++i)
      bfr[i] = *(const bf16x8*)&Bs[buf][q8][wc * 64 + i * 16 + nl][0];
    __builtin_amdgcn_s_setprio(1);
#pragma unroll
    for (int i = 0; i < 4; ++i)
#pragma unroll
      for (int j2 = 0; j2 < 4; ++j2)
        acc[i][j2] = __builtin_amdgcn_mfma_f32_16x16x32_bf16(af[i], bfr[j2], acc[i][j2], 0, 0, 0);
    __builtin_amdgcn_s_setprio(0);
  }
#pragma unroll
  for (int i = 0; i < 4; ++i)
#pragma unroll
    for (int j2 = 0; j2 < 4; ++j2)
#pragma unroll
      for (int r = 0; r < 4; ++r) {
        int row = bm + wr * 64 + i * 16 + q8 * 4 + r;
        int col = bn + wc * 64 + j2 * 16 + nl;
        C[(size_t)row * E_ + col] = f2bf(acc[i][j2][r] * scale);
      }
}

// ---------------- V transpose: v[b*T+t][e] -> vT[b][e][t] ----------------
__global__ void transpose_v(const u16* __restrict__ v, u16* __restrict__ vT) {
  __shared__ u16 lt[64][66];
  int t = threadIdx.x;
  int t0 = blockIdx.x * 64;
  int e0 = blockIdx.y * 64;
  int b = blockIdx.z;
#pragma unroll
  for (int i = 0; i < 2; ++i) {
    int u = t + i * 256;
    int tok = u >> 3, cg = u & 7;
    bf16x8 val = *(const bf16x8*)(v + (size_t)(b * T_ + t0 + tok) * E_ + e0 + cg * 8);
#pragma unroll
    for (int j = 0; j < 8; ++j) lt[tok][cg * 8 + j] = (u16)val[j];
  }
  __syncthreads();
#pragma unroll
  for (int i = 0; i < 2; ++i) {
    int u = t + i * 256;
    int d = u >> 3, ck = u & 7;
    bf16x8 o;
#pragma unroll
    for (int j = 0; j < 8; ++j) o[j] = (short)lt[ck * 8 + j][d];
    *(bf16x8*)(vT + (size_t)(b * E_ + e0 + d) * T_ + t0 + ck * 8) = o;
  }
}

// ---------------- banded flash attention, barrier-free + register prefetch ----------------
__global__ __launch_bounds__(256)
void attn_kernel(const u16* __restrict__ qkv, const u16* __restrict__ vT,
                 float* __restrict__ out) {
  const int Mtot = B_ * T_;
  const u16* qb = qkv;
  const u16* kb = qkv + (size_t)Mtot * E_;

  __shared__ u16 Pl[4][2][16][36];

  int tid = threadIdx.x;
  int lane = tid & 63, wave = tid >> 6;
  int q8 = lane >> 4, nl = lane & 15;
  int qs = blockIdx.x * 128;
  int bh = blockIdx.y;
  int b = bh / H_, h = bh % H_;
  int qw = qs + wave * 32;
  size_t ho = (size_t)h * S_;

  bf16x8 aq[2][2];
#pragma unroll
  for (int mt = 0; mt < 2; ++mt) {
    const u16* qrow = qb + (size_t)(b * T_ + qw + mt * 16 + nl) * E_ + ho;
    aq[mt][0] = *(const bf16x8*)(qrow + q8 * 8);
    aq[mt][1] = *(const bf16x8*)(qrow + 32 + q8 * 8);
  }

  f32x4 O[2][4] = {};
  f32x4 lacc[2] = {};

  int klo = qw - WIN_; if (klo < 0) klo = 0;
  int khi = qw + 32 + WIN_; if (khi > T_) khi = T_;

  const u16* kbase = kb + (size_t)b * T_ * E_ + ho;
  const u16* vbase = vT + (size_t)b * E_ * T_ + ho * T_;

  // prefetch first K tile
  bf16x8 bk[2][2];
#pragma unroll
  for (int nt = 0; nt < 2; ++nt) {
    const u16* krow = kbase + (size_t)(klo + nt * 16 + nl) * E_;
    bk[nt][0] = *(const bf16x8*)(krow + q8 * 8);
    bk[nt][1] = *(const bf16x8*)(krow + 32 + q8 * 8);
  }

  for (int kt = klo; kt < khi; kt += 32) {
    // ---- V loads for THIS round issued early (used after ~400cy chain) ----
    bf16x8 bv[4];
#pragma unroll
    for (int dt = 0; dt < 4; ++dt)
      bv[dt] = *(const bf16x8*)(vbase + (size_t)(dt * 16 + nl) * T_ + kt + q8 * 8);

    // ---- K prefetch for NEXT round (clamped; used next iteration) ----
    int ktn = (kt + 32 < khi) ? kt + 32 : kt;
    bf16x8 nbk[2][2];
#pragma unroll
    for (int nt = 0; nt < 2; ++nt) {
      const u16* krow = kbase + (size_t)(ktn + nt * 16 + nl) * E_;
      nbk[nt][0] = *(const bf16x8*)(krow + q8 * 8);
      nbk[nt][1] = *(const bf16x8*)(krow + 32 + q8 * 8);
    }

    // ---- QK^T ----
    f32x4 sc[2][2] = {};
#pragma unroll
    for (int nt = 0; nt < 2; ++nt)
#pragma unroll
      for (int mt = 0; mt < 2; ++mt) {
        sc[mt][nt] = __builtin_amdgcn_mfma_f32_16x16x32_bf16(aq[mt][0], bk[nt][0], sc[mt][nt], 0, 0, 0);
        sc[mt][nt] = __builtin_amdgcn_mfma_f32_16x16x32_bf16(aq[mt][1], bk[nt][1], sc[mt][nt], 0, 0, 0);
      }

    // ---- band mask on edge tiles only (wave-uniform branch) ----
    if (kt < qw - 225 || kt > qw + 225) {
#pragma unroll
      for (int mt = 0; mt < 2; ++mt)
#pragma unroll
        for (int nt = 0; nt < 2; ++nt)
#pragma unroll
          for (int r = 0; r < 4; ++r) {
            int qa = qw + mt * 16 + q8 * 4 + r;
            int ka = kt + nt * 16 + nl;
            int d = ka - qa;
            sc[mt][nt][r] = (d < -WIN_ || d > WIN_) ? -1e30f : sc[mt][nt][r];
          }
    }

    // ---- fixed-shift softmax, deferred normalization ----
#pragma unroll
    for (int mt = 0; mt < 2; ++mt)
#pragma unroll
      for (int r = 0; r < 4; ++r) {
        float p0 = exp2f(sc[mt][0][r]);
        float p1 = exp2f(sc[mt][1][r]);
        sc[mt][0][r] = p0; sc[mt][1][r] = p1;
        lacc[mt][r] += p0 + p1;
      }

    // ---- P -> LDS roundtrip (C-layout -> A-layout), per-wave ----
#pragma unroll
    for (int mt = 0; mt < 2; ++mt)
#pragma unroll
      for (int r = 0; r < 4; ++r) {
        Pl[wave][mt][q8 * 4 + r][nl] = f2bf(sc[mt][0][r]);
        Pl[wave][mt][q8 * 4 + r][16 + nl] = f2bf(sc[mt][1][r]);
      }

    bf16x8 ap[2];
#pragma unroll
    for (int mt = 0; mt < 2; ++mt) {
      bf16x4 lo = *(const bf16x4*)&Pl[wave][mt][nl][q8 * 8];
      bf16x4 hi = *(const bf16x4*)&Pl[wave][mt][nl][q8 * 8 + 4];
      bf16x8 a;
      a[0] = lo[0]; a[1] = lo[1]; a[2] = lo[2]; a[3] = lo[3];
      a[4] = hi[0]; a[5] = hi[1]; a[6] = hi[2]; a[7] = hi[3];
      ap[mt] = a;
    }

    // ---- P @ V ----
#pragma unroll
    for (int dt = 0; dt < 4; ++dt)
#pragma unroll
      for (int mt = 0; mt < 2; ++mt)
        O[mt][dt] = __builtin_amdgcn_mfma_f32_16x16x32_bf16(ap[mt], bv[dt], O[mt][dt], 0, 0, 0);

    // rotate prefetch
#pragma unroll
    for (int nt = 0; nt < 2; ++nt) {
      bk[nt][0] = nbk[nt][0];
      bk[nt][1] = nbk[nt][1];
    }
  }

  // ---- deferred l-reduction + normalize + store ----
#pragma unroll
  for (int mt = 0; mt < 2; ++mt)
#pragma unroll
    for (int r = 0; r < 4; ++r) {
      float l = lacc[mt][r];
      l += __shfl_xor(l, 1); l += __shfl_xor(l, 2);
      l += __shfl_xor(l, 4); l += __shfl_xor(l, 8);
      float inv = 1.0f / l;
      int qa = qw + mt * 16 + q8 * 4 + r;
      float* op = out + (size_t)(b * T_ + qa) * E_ + ho;
#pragma unroll
      for (int dt = 0; dt < 4; ++dt)
        op[dt * 16 + nl] = O[mt][dt][r] * inv;
    }
}

extern "C" void kernel_launch(void* const* d_in, const int* in_sizes, int n_in,
                              void* d_out, int out_size, void* d_ws, size_t ws_size,
                              hipStream_t stream) {
  const float* x  = (const float*)d_in[0];
  const float* Wq = (const float*)d_in[1];
  const float* Wk = (const float*)d_in[2];
  const float* Wv = (const float*)d_in[3];
  float* out = (float*)d_out;

  const size_t M = (size_t)B_ * T_;
  u16* xb  = (u16*)d_ws;               // M*E bf16; reused as vT after gemm
  u16* wb  = xb + M * E_;              // 3*E*E
  u16* qkv = wb + 3 * (size_t)E_ * E_; // 3*M*E
  u16* vT  = xb;                       // [B][E][T]

  const int n4x = B_ * T_ * E_ / 4;
  const int n4w = E_ * E_ / 4;
  int cvt_blocks = (n4x + 3 * n4w + 255) / 256;
  cvt_all<<<cvt_blocks, 256, 0, stream>>>(x, Wq, Wk, Wv, xb, wb);

  dim3 g1(M / 128, E_ / 128, 3);
  gemm_qkv<<<g1, 256, 0, stream>>>(xb, wb, qkv);

  dim3 gt(T_ / 64, E_ / 64, B_);
  transpose_v<<<gt, 256, 0, stream>>>(qkv + 2 * M * E_, vT);

  dim3 g2(T_ / 128, B_ * H_);
  attn_kernel<<<g2, 256, 0, stream>>>(qkv, vT, out);
}

// Round 2
// 213.403 us; speedup vs baseline: 1.0575x; 1.0575x over previous
//
#include <hip/hip_runtime.h>

#define B_ 2
#define T_ 4096
#define E_ 768
#define H_ 12
#define S_ 64
#define WIN_ 256

typedef unsigned short u16;
typedef unsigned int u32;
typedef __attribute__((ext_vector_type(8))) short bf16x8;
typedef __attribute__((ext_vector_type(4))) short bf16x4;
typedef __attribute__((ext_vector_type(4))) float f32x4;

__device__ __forceinline__ u16 f2bf(float f) {
  u32 u = __float_as_uint(f);
  u += ((u >> 16) & 1u) + 0x7fffu;   // RNE
  return (u16)(u >> 16);
}

__device__ __forceinline__ void async_copy16(const u16* g, u16* l) {
  __builtin_amdgcn_global_load_lds(
      (const __attribute__((address_space(1))) void*)g,
      (__attribute__((address_space(3))) void*)l, 16, 0, 0);
}

// ---------------- fp32 -> bf16, all 4 tensors in one dispatch ----------------
__global__ void cvt_all(const float* __restrict__ x, const float* __restrict__ wq,
                        const float* __restrict__ wk, const float* __restrict__ wv,
                        u16* __restrict__ xb, u16* __restrict__ wb) {
  const int n4x = B_ * T_ * E_ / 4;
  const int n4w = E_ * E_ / 4;
  int i = blockIdx.x * 256 + threadIdx.x;
  const float* src;
  u16* dst;
  int j;
  if (i < n4x) {
    src = x; dst = xb; j = i;
  } else {
    int t = i - n4x;
    int z = t / n4w;
    if (z >= 3) return;
    j = t - z * n4w;
    src = (z == 0) ? wq : ((z == 1) ? wk : wv);
    dst = wb + (size_t)z * E_ * E_;
  }
  float4 v = ((const float4*)src)[j];
  ushort4 o;
  o.x = f2bf(v.x); o.y = f2bf(v.y); o.z = f2bf(v.z); o.w = f2bf(v.w);
  ((ushort4*)dst)[j] = o;
}

// ---------------- QKV projection GEMM: 3-deep LDS ring, counted vmcnt(4) ----------------
// Round-0 (2-buf, syncthreads=vmcnt(0) drain): 76us, MfmaUtil 14, occ 29%.
// Round-1 (4-buf, 64KB): 86us -- occupancy fell to 1.3 blocks/CU and killed TLP.
// This version: 3-buf (48KB -> 3 blocks/CU, same TLP as round-0) + depth-2
// prefetch (waited-on loads were issued TWO iterations earlier) + hand-unrolled
// 3-step loop so all LDS buffer indices are compile-time (ds_read offsets fold
// to immediates; less per-iter VALU).
__global__ __launch_bounds__(256)
void gemm_qkv(const u16* __restrict__ xb, const u16* __restrict__ wb,
              u16* __restrict__ qkv) {
  const int M = B_ * T_;
  __shared__ u16 As[3][4][128][8];   // [buf][kchunk][row][8]  24KB
  __shared__ u16 Bs[3][4][128][8];   // 24KB
  int tid = threadIdx.x;
  int lane = tid & 63, wave = tid >> 6;
  int wr = wave >> 1, wc = wave & 1;
  int q8 = lane >> 4, nl = lane & 15;
  int bm = blockIdx.x * 128, bn = blockIdx.y * 128;
  int z = blockIdx.z;
  const u16* A = xb;
  const u16* Bmat = wb + (size_t)z * E_ * E_;
  u16* C = qkv + (size_t)z * M * E_;
  float scale = (z == 0) ? (0.125f * 1.44269504088896f) : 1.0f;

  // staging addresses for this thread (2 A slots + 2 B slots)
  int ch0 = tid >> 7, row0 = tid & 127;
  int u1 = tid + 256;
  int ch1 = u1 >> 7, row1 = u1 & 127;
  const u16* ga0 = A + (size_t)(bm + row0) * E_ + ch0 * 8;
  const u16* ga1 = A + (size_t)(bm + row1) * E_ + ch1 * 8;
  const u16* gb0 = Bmat + (size_t)(bn + row0) * E_ + ch0 * 8;
  const u16* gb1 = Bmat + (size_t)(bn + row1) * E_ + ch1 * 8;

  const int NK = E_ / 32;   // 24, divisible by 3
  // prologue: stage tiles 0,1 into bufs 0,1 (8 loads in flight per thread)
#pragma unroll
  for (int p = 0; p < 2; ++p) {
    int koff = p * 32;
    async_copy16(ga0 + koff, &As[p][ch0][row0][0]);
    async_copy16(ga1 + koff, &As[p][ch1][row1][0]);
    async_copy16(gb0 + koff, &Bs[p][ch0][row0][0]);
    async_copy16(gb1 + koff, &Bs[p][ch1][row1][0]);
  }

  f32x4 acc[4][4] = {};

  // One K-step. BUF/PBUF are compile-time constants.
  // Entering: 8 loads outstanding (tiles ki, ki+1). vmcnt(4) -> tile ki landed
  // (issued 2 iters ago); tile ki+1's 4 loads stay in flight across the barrier.
  // After barrier: issue tile ki+2 into PBUF=(ki+2)%3 (overwrites buf (ki-1)%3,
  // whose reads completed before this barrier). Clamp duplicates at the tail
  // land only in buffers that are never read again (ki=NK-2 -> buf0 after its
  // last read; ki=NK-1 -> buf1 after its last read).
#define KSTEP(KI, BUF, PBUF)                                                   \
  {                                                                            \
    asm volatile("s_waitcnt vmcnt(4) lgkmcnt(0)" ::: "memory");                \
    __builtin_amdgcn_s_barrier();                                              \
    __builtin_amdgcn_sched_barrier(0);                                         \
    int kp = ((KI) + 2 < NK) ? (KI) + 2 : NK - 1;                              \
    int koff = kp * 32;                                                        \
    async_copy16(ga0 + koff, &As[PBUF][ch0][row0][0]);                         \
    async_copy16(ga1 + koff, &As[PBUF][ch1][row1][0]);                         \
    async_copy16(gb0 + koff, &Bs[PBUF][ch0][row0][0]);                         \
    async_copy16(gb1 + koff, &Bs[PBUF][ch1][row1][0]);                         \
    bf16x8 af[4], bfr[4];                                                      \
    _Pragma("unroll")                                                          \
    for (int i = 0; i < 4; ++i)                                                \
      af[i] = *(const bf16x8*)&As[BUF][q8][wr * 64 + i * 16 + nl][0];          \
    _Pragma("unroll")                                                          \
    for (int i = 0; i < 4; ++i)                                                \
      bfr[i] = *(const bf16x8*)&Bs[BUF][q8][wc * 64 + i * 16 + nl][0];         \
    __builtin_amdgcn_s_setprio(1);                                             \
    _Pragma("unroll")                                                          \
    for (int i = 0; i < 4; ++i)                                                \
      _Pragma("unroll")                                                        \
      for (int j2 = 0; j2 < 4; ++j2)                                           \
        acc[i][j2] = __builtin_amdgcn_mfma_f32_16x16x32_bf16(af[i], bfr[j2],   \
                                                             acc[i][j2], 0, 0, 0); \
    __builtin_amdgcn_s_setprio(0);                                             \
  }

  for (int kb = 0; kb < NK; kb += 3) {
    KSTEP(kb + 0, 0, 2)
    KSTEP(kb + 1, 1, 0)
    KSTEP(kb + 2, 2, 1)
  }
#undef KSTEP

#pragma unroll
  for (int i = 0; i < 4; ++i)
#pragma unroll
    for (int j2 = 0; j2 < 4; ++j2)
#pragma unroll
      for (int r = 0; r < 4; ++r) {
        int row = bm + wr * 64 + i * 16 + q8 * 4 + r;
        int col = bn + wc * 64 + j2 * 16 + nl;
        C[(size_t)row * E_ + col] = f2bf(acc[i][j2][r] * scale);
      }
}

// ---------------- V transpose: v[b*T+t][e] -> vT[b][e][t] ----------------
__global__ void transpose_v(const u16* __restrict__ v, u16* __restrict__ vT) {
  __shared__ u16 lt[64][66];
  int t = threadIdx.x;
  int t0 = blockIdx.x * 64;
  int e0 = blockIdx.y * 64;
  int b = blockIdx.z;
#pragma unroll
  for (int i = 0; i < 2; ++i) {
    int u = t + i * 256;
    int tok = u >> 3, cg = u & 7;
    bf16x8 val = *(const bf16x8*)(v + (size_t)(b * T_ + t0 + tok) * E_ + e0 + cg * 8);
#pragma unroll
    for (int j = 0; j < 8; ++j) lt[tok][cg * 8 + j] = (u16)val[j];
  }
  __syncthreads();
#pragma unroll
  for (int i = 0; i < 2; ++i) {
    int u = t + i * 256;
    int d = u >> 3, ck = u & 7;
    bf16x8 o;
#pragma unroll
    for (int j = 0; j < 8; ++j) o[j] = (short)lt[ck * 8 + j][d];
    *(bf16x8*)(vT + (size_t)(b * E_ + e0 + d) * T_ + t0 + ck * 8) = o;
  }
}

// ---------------- banded flash attention, barrier-free + register prefetch ----------------
__global__ __launch_bounds__(256)
void attn_kernel(const u16* __restrict__ qkv, const u16* __restrict__ vT,
                 float* __restrict__ out) {
  const int Mtot = B_ * T_;
  const u16* qb = qkv;
  const u16* kb = qkv + (size_t)Mtot * E_;

  __shared__ u16 Pl[4][2][16][36];

  int tid = threadIdx.x;
  int lane = tid & 63, wave = tid >> 6;
  int q8 = lane >> 4, nl = lane & 15;
  int qs = blockIdx.x * 128;
  int bh = blockIdx.y;
  int b = bh / H_, h = bh % H_;
  int qw = qs + wave * 32;
  size_t ho = (size_t)h * S_;

  bf16x8 aq[2][2];
#pragma unroll
  for (int mt = 0; mt < 2; ++mt) {
    const u16* qrow = qb + (size_t)(b * T_ + qw + mt * 16 + nl) * E_ + ho;
    aq[mt][0] = *(const bf16x8*)(qrow + q8 * 8);
    aq[mt][1] = *(const bf16x8*)(qrow + 32 + q8 * 8);
  }

  f32x4 O[2][4] = {};
  f32x4 lacc[2] = {};

  int klo = qw - WIN_; if (klo < 0) klo = 0;
  int khi = qw + 32 + WIN_; if (khi > T_) khi = T_;

  const u16* kbase = kb + (size_t)b * T_ * E_ + ho;
  const u16* vbase = vT + (size_t)b * E_ * T_ + ho * T_;

  // prefetch first K tile
  bf16x8 bk[2][2];
#pragma unroll
  for (int nt = 0; nt < 2; ++nt) {
    const u16* krow = kbase + (size_t)(klo + nt * 16 + nl) * E_;
    bk[nt][0] = *(const bf16x8*)(krow + q8 * 8);
    bk[nt][1] = *(const bf16x8*)(krow + 32 + q8 * 8);
  }

  for (int kt = klo; kt < khi; kt += 32) {
    // ---- V loads for THIS round issued early (used after ~400cy chain) ----
    bf16x8 bv[4];
#pragma unroll
    for (int dt = 0; dt < 4; ++dt)
      bv[dt] = *(const bf16x8*)(vbase + (size_t)(dt * 16 + nl) * T_ + kt + q8 * 8);

    // ---- K prefetch for NEXT round (clamped; used next iteration) ----
    int ktn = (kt + 32 < khi) ? kt + 32 : kt;
    bf16x8 nbk[2][2];
#pragma unroll
    for (int nt = 0; nt < 2; ++nt) {
      const u16* krow = kbase + (size_t)(ktn + nt * 16 + nl) * E_;
      nbk[nt][0] = *(const bf16x8*)(krow + q8 * 8);
      nbk[nt][1] = *(const bf16x8*)(krow + 32 + q8 * 8);
    }

    // ---- QK^T ----
    f32x4 sc[2][2] = {};
#pragma unroll
    for (int nt = 0; nt < 2; ++nt)
#pragma unroll
      for (int mt = 0; mt < 2; ++mt) {
        sc[mt][nt] = __builtin_amdgcn_mfma_f32_16x16x32_bf16(aq[mt][0], bk[nt][0], sc[mt][nt], 0, 0, 0);
        sc[mt][nt] = __builtin_amdgcn_mfma_f32_16x16x32_bf16(aq[mt][1], bk[nt][1], sc[mt][nt], 0, 0, 0);
      }

    // ---- band mask on edge tiles only (wave-uniform branch) ----
    if (kt < qw - 225 || kt > qw + 225) {
#pragma unroll
      for (int mt = 0; mt < 2; ++mt)
#pragma unroll
        for (int nt = 0; nt < 2; ++nt)
#pragma unroll
          for (int r = 0; r < 4; ++r) {
            int qa = qw + mt * 16 + q8 * 4 + r;
            int ka = kt + nt * 16 + nl;
            int d = ka - qa;
            sc[mt][nt][r] = (d < -WIN_ || d > WIN_) ? -1e30f : sc[mt][nt][r];
          }
    }

    // ---- fixed-shift softmax, deferred normalization ----
#pragma unroll
    for (int mt = 0; mt < 2; ++mt)
#pragma unroll
      for (int r = 0; r < 4; ++r) {
        float p0 = exp2f(sc[mt][0][r]);
        float p1 = exp2f(sc[mt][1][r]);
        sc[mt][0][r] = p0; sc[mt][1][r] = p1;
        lacc[mt][r] += p0 + p1;
      }

    // ---- P -> LDS roundtrip (C-layout -> A-layout), per-wave ----
#pragma unroll
    for (int mt = 0; mt < 2; ++mt)
#pragma unroll
      for (int r = 0; r < 4; ++r) {
        Pl[wave][mt][q8 * 4 + r][nl] = f2bf(sc[mt][0][r]);
        Pl[wave][mt][q8 * 4 + r][16 + nl] = f2bf(sc[mt][1][r]);
      }

    bf16x8 ap[2];
#pragma unroll
    for (int mt = 0; mt < 2; ++mt) {
      bf16x4 lo = *(const bf16x4*)&Pl[wave][mt][nl][q8 * 8];
      bf16x4 hi = *(const bf16x4*)&Pl[wave][mt][nl][q8 * 8 + 4];
      bf16x8 a;
      a[0] = lo[0]; a[1] = lo[1]; a[2] = lo[2]; a[3] = lo[3];
      a[4] = hi[0]; a[5] = hi[1]; a[6] = hi[2]; a[7] = hi[3];
      ap[mt] = a;
    }

    // ---- P @ V ----
#pragma unroll
    for (int dt = 0; dt < 4; ++dt)
#pragma unroll
      for (int mt = 0; mt < 2; ++mt)
        O[mt][dt] = __builtin_amdgcn_mfma_f32_16x16x32_bf16(ap[mt], bv[dt], O[mt][dt], 0, 0, 0);

    // rotate prefetch
#pragma unroll
    for (int nt = 0; nt < 2; ++nt) {
      bk[nt][0] = nbk[nt][0];
      bk[nt][1] = nbk[nt][1];
    }
  }

  // ---- deferred l-reduction + normalize + store ----
#pragma unroll
  for (int mt = 0; mt < 2; ++mt)
#pragma unroll
    for (int r = 0; r < 4; ++r) {
      float l = lacc[mt][r];
      l += __shfl_xor(l, 1); l += __shfl_xor(l, 2);
      l += __shfl_xor(l, 4); l += __shfl_xor(l, 8);
      float inv = 1.0f / l;
      int qa = qw + mt * 16 + q8 * 4 + r;
      float* op = out + (size_t)(b * T_ + qa) * E_ + ho;
#pragma unroll
      for (int dt = 0; dt < 4; ++dt)
        op[dt * 16 + nl] = O[mt][dt][r] * inv;
    }
}

extern "C" void kernel_launch(void* const* d_in, const int* in_sizes, int n_in,
                              void* d_out, int out_size, void* d_ws, size_t ws_size,
                              hipStream_t stream) {
  const float* x  = (const float*)d_in[0];
  const float* Wq = (const float*)d_in[1];
  const float* Wk = (const float*)d_in[2];
  const float* Wv = (const float*)d_in[3];
  float* out = (float*)d_out;

  const size_t M = (size_t)B_ * T_;
  u16* xb  = (u16*)d_ws;               // M*E bf16; reused as vT after gemm
  u16* wb  = xb + M * E_;              // 3*E*E
  u16* qkv = wb + 3 * (size_t)E_ * E_; // 3*M*E
  u16* vT  = xb;                       // [B][E][T]

  const int n4x = B_ * T_ * E_ / 4;
  const int n4w = E_ * E_ / 4;
  int cvt_blocks = (n4x + 3 * n4w + 255) / 256;
  cvt_all<<<cvt_blocks, 256, 0, stream>>>(x, Wq, Wk, Wv, xb, wb);

  dim3 g1(M / 128, E_ / 128, 3);
  gemm_qkv<<<g1, 256, 0, stream>>>(xb, wb, qkv);

  dim3 gt(T_ / 64, E_ / 64, B_);
  transpose_v<<<gt, 256, 0, stream>>>(qkv + 2 * M * E_, vT);

  dim3 g2(T_ / 128, B_ * H_);
  attn_kernel<<<g2, 256, 0, stream>>>(qkv, vT, out);
}

// Round 3
// 185.189 us; speedup vs baseline: 1.2186x; 1.1524x over previous
//
#include <hip/hip_runtime.h>

#define B_ 2
#define T_ 4096
#define E_ 768
#define H_ 12
#define S_ 64
#define WIN_ 256

typedef unsigned short u16;
typedef unsigned int u32;
typedef __attribute__((ext_vector_type(8))) short bf16x8;
typedef __attribute__((ext_vector_type(4))) short bf16x4;
typedef __attribute__((ext_vector_type(4))) float f32x4;

__device__ __forceinline__ u16 f2bf(float f) {
  u32 u = __float_as_uint(f);
  u += ((u >> 16) & 1u) + 0x7fffu;   // RNE
  return (u16)(u >> 16);
}

__device__ __forceinline__ void async_copy16(const u16* g, u16* l) {
  __builtin_amdgcn_global_load_lds(
      (const __attribute__((address_space(1))) void*)g,
      (__attribute__((address_space(3))) void*)l, 16, 0, 0);
}

// ---------------- fp32 -> bf16, all 4 tensors in one dispatch ----------------
__global__ void cvt_all(const float* __restrict__ x, const float* __restrict__ wq,
                        const float* __restrict__ wk, const float* __restrict__ wv,
                        u16* __restrict__ xb, u16* __restrict__ wb) {
  const int n4x = B_ * T_ * E_ / 4;
  const int n4w = E_ * E_ / 4;
  int i = blockIdx.x * 256 + threadIdx.x;
  const float* src;
  u16* dst;
  int j;
  if (i < n4x) {
    src = x; dst = xb; j = i;
  } else {
    int t = i - n4x;
    int z = t / n4w;
    if (z >= 3) return;
    j = t - z * n4w;
    src = (z == 0) ? wq : ((z == 1) ? wk : wv);
    dst = wb + (size_t)z * E_ * E_;
  }
  float4 v = ((const float4*)src)[j];
  ushort4 o;
  o.x = f2bf(v.x); o.y = f2bf(v.y); o.z = f2bf(v.z); o.w = f2bf(v.w);
  ((ushort4*)dst)[j] = o;
}

// ---------------- QKV projection GEMM ----------------
// Rounds 0-2 were pinned at ~76us regardless of pipeline depth/occupancy:
// staging had lane==row -> 1536B stride -> 64 cache lines PER global_load_lds
// (1024 line-requests per block-step; L1 request-rate bound).
// This version: row-major LDS tiles [128][32] so a staging instruction's 64
// lanes cover 16 rows x 64B contiguous -> 16 lines/instr (4x fewer).
// Both-sides XOR chunk swizzle (stage chunk c^(row&3) into slot c; read frag
// chunk q8 at slot q8^(row&3)) keeps ds_read_b128 bank-even.
// Ring structure (3-deep, counted vmcnt(4)) unchanged from round-2.
__global__ __launch_bounds__(256)
void gemm_qkv(const u16* __restrict__ xb, const u16* __restrict__ wb,
              u16* __restrict__ qkv) {
  const int M = B_ * T_;
  __shared__ u16 As[3][128][32];   // [buf][row][k]  24KB, 64B rows
  __shared__ u16 Bs[3][128][32];   // 24KB
  int tid = threadIdx.x;
  int lane = tid & 63, wave = tid >> 6;
  int wr = wave >> 1, wc = wave & 1;
  int q8 = lane >> 4, nl = lane & 15;
  int bm = blockIdx.x * 128, bn = blockIdx.y * 128;
  int z = blockIdx.z;
  const u16* A = xb;
  const u16* Bmat = wb + (size_t)z * E_ * E_;
  u16* C = qkv + (size_t)z * M * E_;
  float scale = (z == 0) ? (0.125f * 1.44269504088896f) : 1.0f;

  // staging: slot s in [0,512) covers row=s>>2, chunk-slot c=s&3 of a tile.
  // thread t owns slots t and t+256 for A and likewise for B.
  // global chunk staged into slot c is cs = c ^ (row&3); row&3 identical for
  // rows r0 and r0+64, so cs is shared.
  int r0 = tid >> 2, c0 = tid & 3;
  int cs = c0 ^ (r0 & 3);
  const u16* ga0 = A + (size_t)(bm + r0) * E_ + cs * 8;
  const u16* ga1 = A + (size_t)(bm + r0 + 64) * E_ + cs * 8;
  const u16* gb0 = Bmat + (size_t)(bn + r0) * E_ + cs * 8;
  const u16* gb1 = Bmat + (size_t)(bn + r0 + 64) * E_ + cs * 8;
  // linear LDS dests: slot s -> byte offset s*16
  int l0 = tid * 8;          // u16 offset of slot t
  int l1 = tid * 8 + 2048;   // slot t+256

  // fragment read swizzle: chunk q8 of row ra lives at slot q8^(ra&3);
  // ra&3 == nl&3 for all fragment rows (wr*64, i*16 are multiples of 4).
  int swz8 = (q8 ^ (nl & 3)) * 8;

  const int NK = E_ / 32;   // 24, divisible by 3
  // prologue: stage tiles 0,1 into bufs 0,1 (8 loads in flight per thread)
#pragma unroll
  for (int p = 0; p < 2; ++p) {
    int koff = p * 32;
    async_copy16(ga0 + koff, &As[p][0][0] + l0);
    async_copy16(ga1 + koff, &As[p][0][0] + l1);
    async_copy16(gb0 + koff, &Bs[p][0][0] + l0);
    async_copy16(gb1 + koff, &Bs[p][0][0] + l1);
  }

  f32x4 acc[4][4] = {};

  // Entering each step: 8 loads outstanding (tiles ki, ki+1). vmcnt(4) ->
  // tile ki landed (issued 2 iters ago); tile ki+1 stays in flight across the
  // barrier. After the barrier, issue tile ki+2 into buf (ki+2)%3 (its reads
  // as tile ki-1 completed before this barrier). Tail clamps land only in
  // buffers never read again.
#define KSTEP(KI, BUF, PBUF)                                                   \
  {                                                                            \
    asm volatile("s_waitcnt vmcnt(4) lgkmcnt(0)" ::: "memory");                \
    __builtin_amdgcn_s_barrier();                                              \
    __builtin_amdgcn_sched_barrier(0);                                         \
    int kp = ((KI) + 2 < NK) ? (KI) + 2 : NK - 1;                              \
    int koff = kp * 32;                                                        \
    async_copy16(ga0 + koff, &As[PBUF][0][0] + l0);                            \
    async_copy16(ga1 + koff, &As[PBUF][0][0] + l1);                            \
    async_copy16(gb0 + koff, &Bs[PBUF][0][0] + l0);                            \
    async_copy16(gb1 + koff, &Bs[PBUF][0][0] + l1);                            \
    bf16x8 af[4], bfr[4];                                                      \
    _Pragma("unroll")                                                          \
    for (int i = 0; i < 4; ++i)                                                \
      af[i] = *(const bf16x8*)&As[BUF][wr * 64 + i * 16 + nl][swz8];           \
    _Pragma("unroll")                                                          \
    for (int i = 0; i < 4; ++i)                                                \
      bfr[i] = *(const bf16x8*)&Bs[BUF][wc * 64 + i * 16 + nl][swz8];          \
    __builtin_amdgcn_s_setprio(1);                                             \
    _Pragma("unroll")                                                          \
    for (int i = 0; i < 4; ++i)                                                \
      _Pragma("unroll")                                                        \
      for (int j2 = 0; j2 < 4; ++j2)                                           \
        acc[i][j2] = __builtin_amdgcn_mfma_f32_16x16x32_bf16(af[i], bfr[j2],   \
                                                             acc[i][j2], 0, 0, 0); \
    __builtin_amdgcn_s_setprio(0);                                             \
  }

  for (int kb = 0; kb < NK; kb += 3) {
    KSTEP(kb + 0, 0, 2)
    KSTEP(kb + 1, 1, 0)
    KSTEP(kb + 2, 2, 1)
  }
#undef KSTEP

#pragma unroll
  for (int i = 0; i < 4; ++i)
#pragma unroll
    for (int j2 = 0; j2 < 4; ++j2)
#pragma unroll
      for (int r = 0; r < 4; ++r) {
        int row = bm + wr * 64 + i * 16 + q8 * 4 + r;
        int col = bn + wc * 64 + j2 * 16 + nl;
        C[(size_t)row * E_ + col] = f2bf(acc[i][j2][r] * scale);
      }
}

// ---------------- V transpose: v[b*T+t][e] -> vT[b][e][t] ----------------
__global__ void transpose_v(const u16* __restrict__ v, u16* __restrict__ vT) {
  __shared__ u16 lt[64][66];
  int t = threadIdx.x;
  int t0 = blockIdx.x * 64;
  int e0 = blockIdx.y * 64;
  int b = blockIdx.z;
#pragma unroll
  for (int i = 0; i < 2; ++i) {
    int u = t + i * 256;
    int tok = u >> 3, cg = u & 7;
    bf16x8 val = *(const bf16x8*)(v + (size_t)(b * T_ + t0 + tok) * E_ + e0 + cg * 8);
#pragma unroll
    for (int j = 0; j < 8; ++j) lt[tok][cg * 8 + j] = (u16)val[j];
  }
  __syncthreads();
#pragma unroll
  for (int i = 0; i < 2; ++i) {
    int u = t + i * 256;
    int d = u >> 3, ck = u & 7;
    bf16x8 o;
#pragma unroll
    for (int j = 0; j < 8; ++j) o[j] = (short)lt[ck * 8 + j][d];
    *(bf16x8*)(vT + (size_t)(b * E_ + e0 + d) * T_ + t0 + ck * 8) = o;
  }
}

// ---------------- banded flash attention, barrier-free + register prefetch ----------------
__global__ __launch_bounds__(256)
void attn_kernel(const u16* __restrict__ qkv, const u16* __restrict__ vT,
                 float* __restrict__ out) {
  const int Mtot = B_ * T_;
  const u16* qb = qkv;
  const u16* kb = qkv + (size_t)Mtot * E_;

  __shared__ u16 Pl[4][2][16][36];

  int tid = threadIdx.x;
  int lane = tid & 63, wave = tid >> 6;
  int q8 = lane >> 4, nl = lane & 15;
  int qs = blockIdx.x * 128;
  int bh = blockIdx.y;
  int b = bh / H_, h = bh % H_;
  int qw = qs + wave * 32;
  size_t ho = (size_t)h * S_;

  bf16x8 aq[2][2];
#pragma unroll
  for (int mt = 0; mt < 2; ++mt) {
    const u16* qrow = qb + (size_t)(b * T_ + qw + mt * 16 + nl) * E_ + ho;
    aq[mt][0] = *(const bf16x8*)(qrow + q8 * 8);
    aq[mt][1] = *(const bf16x8*)(qrow + 32 + q8 * 8);
  }

  f32x4 O[2][4] = {};
  f32x4 lacc[2] = {};

  int klo = qw - WIN_; if (klo < 0) klo = 0;
  int khi = qw + 32 + WIN_; if (khi > T_) khi = T_;

  const u16* kbase = kb + (size_t)b * T_ * E_ + ho;
  const u16* vbase = vT + (size_t)b * E_ * T_ + ho * T_;

  // prefetch first K tile
  bf16x8 bk[2][2];
#pragma unroll
  for (int nt = 0; nt < 2; ++nt) {
    const u16* krow = kbase + (size_t)(klo + nt * 16 + nl) * E_;
    bk[nt][0] = *(const bf16x8*)(krow + q8 * 8);
    bk[nt][1] = *(const bf16x8*)(krow + 32 + q8 * 8);
  }

  for (int kt = klo; kt < khi; kt += 32) {
    // ---- V loads for THIS round issued early (used after ~400cy chain) ----
    bf16x8 bv[4];
#pragma unroll
    for (int dt = 0; dt < 4; ++dt)
      bv[dt] = *(const bf16x8*)(vbase + (size_t)(dt * 16 + nl) * T_ + kt + q8 * 8);

    // ---- K prefetch for NEXT round (clamped; used next iteration) ----
    int ktn = (kt + 32 < khi) ? kt + 32 : kt;
    bf16x8 nbk[2][2];
#pragma unroll
    for (int nt = 0; nt < 2; ++nt) {
      const u16* krow = kbase + (size_t)(ktn + nt * 16 + nl) * E_;
      nbk[nt][0] = *(const bf16x8*)(krow + q8 * 8);
      nbk[nt][1] = *(const bf16x8*)(krow + 32 + q8 * 8);
    }

    // ---- QK^T ----
    f32x4 sc[2][2] = {};
#pragma unroll
    for (int nt = 0; nt < 2; ++nt)
#pragma unroll
      for (int mt = 0; mt < 2; ++mt) {
        sc[mt][nt] = __builtin_amdgcn_mfma_f32_16x16x32_bf16(aq[mt][0], bk[nt][0], sc[mt][nt], 0, 0, 0);
        sc[mt][nt] = __builtin_amdgcn_mfma_f32_16x16x32_bf16(aq[mt][1], bk[nt][1], sc[mt][nt], 0, 0, 0);
      }

    // ---- band mask on edge tiles only (wave-uniform branch) ----
    if (kt < qw - 225 || kt > qw + 225) {
#pragma unroll
      for (int mt = 0; mt < 2; ++mt)
#pragma unroll
        for (int nt = 0; nt < 2; ++nt)
#pragma unroll
          for (int r = 0; r < 4; ++r) {
            int qa = qw + mt * 16 + q8 * 4 + r;
            int ka = kt + nt * 16 + nl;
            int d = ka - qa;
            sc[mt][nt][r] = (d < -WIN_ || d > WIN_) ? -1e30f : sc[mt][nt][r];
          }
    }

    // ---- fixed-shift softmax, deferred normalization ----
#pragma unroll
    for (int mt = 0; mt < 2; ++mt)
#pragma unroll
      for (int r = 0; r < 4; ++r) {
        float p0 = exp2f(sc[mt][0][r]);
        float p1 = exp2f(sc[mt][1][r]);
        sc[mt][0][r] = p0; sc[mt][1][r] = p1;
        lacc[mt][r] += p0 + p1;
      }

    // ---- P -> LDS roundtrip (C-layout -> A-layout), per-wave ----
#pragma unroll
    for (int mt = 0; mt < 2; ++mt)
#pragma unroll
      for (int r = 0; r < 4; ++r) {
        Pl[wave][mt][q8 * 4 + r][nl] = f2bf(sc[mt][0][r]);
        Pl[wave][mt][q8 * 4 + r][16 + nl] = f2bf(sc[mt][1][r]);
      }

    bf16x8 ap[2];
#pragma unroll
    for (int mt = 0; mt < 2; ++mt) {
      bf16x4 lo = *(const bf16x4*)&Pl[wave][mt][nl][q8 * 8];
      bf16x4 hi = *(const bf16x4*)&Pl[wave][mt][nl][q8 * 8 + 4];
      bf16x8 a;
      a[0] = lo[0]; a[1] = lo[1]; a[2] = lo[2]; a[3] = lo[3];
      a[4] = hi[0]; a[5] = hi[1]; a[6] = hi[2]; a[7] = hi[3];
      ap[mt] = a;
    }

    // ---- P @ V ----
#pragma unroll
    for (int dt = 0; dt < 4; ++dt)
#pragma unroll
      for (int mt = 0; mt < 2; ++mt)
        O[mt][dt] = __builtin_amdgcn_mfma_f32_16x16x32_bf16(ap[mt], bv[dt], O[mt][dt], 0, 0, 0);

    // rotate prefetch
#pragma unroll
    for (int nt = 0; nt < 2; ++nt) {
      bk[nt][0] = nbk[nt][0];
      bk[nt][1] = nbk[nt][1];
    }
  }

  // ---- deferred l-reduction + normalize + store ----
#pragma unroll
  for (int mt = 0; mt < 2; ++mt)
#pragma unroll
    for (int r = 0; r < 4; ++r) {
      float l = lacc[mt][r];
      l += __shfl_xor(l, 1); l += __shfl_xor(l, 2);
      l += __shfl_xor(l, 4); l += __shfl_xor(l, 8);
      float inv = 1.0f / l;
      int qa = qw + mt * 16 + q8 * 4 + r;
      float* op = out + (size_t)(b * T_ + qa) * E_ + ho;
#pragma unroll
      for (int dt = 0; dt < 4; ++dt)
        op[dt * 16 + nl] = O[mt][dt][r] * inv;
    }
}

extern "C" void kernel_launch(void* const* d_in, const int* in_sizes, int n_in,
                              void* d_out, int out_size, void* d_ws, size_t ws_size,
                              hipStream_t stream) {
  const float* x  = (const float*)d_in[0];
  const float* Wq = (const float*)d_in[1];
  const float* Wk = (const float*)d_in[2];
  const float* Wv = (const float*)d_in[3];
  float* out = (float*)d_out;

  const size_t M = (size_t)B_ * T_;
  u16* xb  = (u16*)d_ws;               // M*E bf16; reused as vT after gemm
  u16* wb  = xb + M * E_;              // 3*E*E
  u16* qkv = wb + 3 * (size_t)E_ * E_; // 3*M*E
  u16* vT  = xb;                       // [B][E][T]

  const int n4x = B_ * T_ * E_ / 4;
  const int n4w = E_ * E_ / 4;
  int cvt_blocks = (n4x + 3 * n4w + 255) / 256;
  cvt_all<<<cvt_blocks, 256, 0, stream>>>(x, Wq, Wk, Wv, xb, wb);

  dim3 g1(M / 128, E_ / 128, 3);
  gemm_qkv<<<g1, 256, 0, stream>>>(xb, wb, qkv);

  dim3 gt(T_ / 64, E_ / 64, B_);
  transpose_v<<<gt, 256, 0, stream>>>(qkv + 2 * M * E_, vT);

  dim3 g2(T_ / 128, B_ * H_);
  attn_kernel<<<g2, 256, 0, stream>>>(qkv, vT, out);
}